// Round 5
// baseline (582.426 us; speedup 1.0000x reference)
//
#include <hip/hip_runtime.h>
#include <cstdint>

#define DIM 128
#define MTILE 64        // edges per block-tile
#define PAIR_LD 264     // ushorts per pair row (256 + 8 pad, keeps 16B align)
#define H_LD 136        // ushorts per h row  (128 + 8 pad)

typedef __bf16 v8bf __attribute__((ext_vector_type(8)));
typedef float v16f __attribute__((ext_vector_type(16)));

static __device__ __forceinline__ unsigned int f2bf_pack(float a, float b) {
  union { float f; unsigned u; } x, y; x.f = a; y.f = b;
  unsigned lo = (x.u + 0x7FFFu + ((x.u >> 16) & 1u)) >> 16;
  unsigned hi = (y.u + 0x7FFFu + ((y.u >> 16) & 1u)) >> 16;
  return lo | (hi << 16);
}
static __device__ __forceinline__ unsigned short f2bf(float a) {
  union { float f; unsigned u; } x; x.f = a;
  return (unsigned short)((x.u + 0x7FFFu + ((x.u >> 16) & 1u)) >> 16);
}
static __device__ __forceinline__ float bfhi2f(unsigned int hi16) {
  union { unsigned u; float f; } c; c.u = hi16; return c.f;
}

// One fused prep launch:
//  [0, 32768)          : W1 [256][128] -> W1t bf16 [128][256] (transpose+convert)
//  [32768, 49152)      : W2 [128][128] -> W2t bf16 [128][128]
//  [49152, 49152+n8)   : x1 fp32 -> xc1 bf16, 8 elems/thread
//  [.., 49152+2*n8)    : x2 fp32 -> xc2 bf16
__global__ __launch_bounds__(256) void prep_all(
    const float* __restrict__ W1, const float* __restrict__ W2,
    const float* __restrict__ x1, const float* __restrict__ x2,
    unsigned short* __restrict__ W1t, unsigned short* __restrict__ W2t,
    unsigned short* __restrict__ xc1, unsigned short* __restrict__ xc2,
    int n8, int use_cache) {
  int i = blockIdx.x * 256 + threadIdx.x;
  if (i < 32768) {
    int n = i >> 8, k = i & 255;
    W1t[i] = f2bf(W1[k * 128 + n]);
  } else if (i < 49152) {
    int j = i - 32768;
    int n = j >> 7, k = j & 127;
    W2t[j] = f2bf(W2[k * 128 + n]);
  } else if (use_cache) {
    int j = i - 49152;
    const float* xs;
    unsigned short* xd;
    if (j < n8) { xs = x1; xd = xc1; }
    else if (j < 2 * n8) { xs = x2; xd = xc2; j -= n8; }
    else return;
    const float4* s = reinterpret_cast<const float4*>(xs) + (size_t)j * 2;
    float4 f0 = s[0];
    float4 f1 = s[1];
    uint4 pk;
    pk.x = f2bf_pack(f0.x, f0.y);
    pk.y = f2bf_pack(f0.z, f0.w);
    pk.z = f2bf_pack(f1.x, f1.y);
    pk.w = f2bf_pack(f1.z, f1.w);
    reinterpret_cast<uint4*>(xd)[j] = pk;
  }
}

// Main kernel, round-5 structure:
//  GEMM1: h1 = relu(pair @ W1) -> LDS (normal [m][k] layout)
//  GEMM2: h2^T = W2t @ h1^T -> stays in REGISTERS (A = persistent B2 frags,
//         B-frags read from sm_h1 with the same ds_read_b128 pattern as GEMM1)
//  GEMM3: in-register dot with per-lane W3/b2 constants + shfl_xor(32),
//         1KB partial buffer, 4-way cross-wave reduce deferred to next iter.
// LESSONS kept: no gather payload live across MFMA sections (r2/r3 spills);
// bf16 node cache; depth-1 idx prefetch; end-of-loop x-row loads live only
// across partial-store + barrier.
__global__ __launch_bounds__(256, 2) void mlp_edge_cached(
    const int* __restrict__ eidx,
    const unsigned short* __restrict__ W1t, const unsigned short* __restrict__ W2t,
    const float* __restrict__ b1, const float* __restrict__ b2,
    const float* __restrict__ W3, const float* __restrict__ b3,
    float* __restrict__ out, int E, int ntiles,
    const unsigned short* __restrict__ xc1, const unsigned short* __restrict__ xc2)
{
  __shared__ unsigned short sm_pair[MTILE * PAIR_LD];  // 33792 B
  __shared__ unsigned short sm_h1[MTILE * H_LD];       // 17408 B
  __shared__ float sm_part[4 * MTILE];                 // 1024 B: [wave][edge]

  const int tid = threadIdx.x;
  const int lane = tid & 63;
  const int wv = tid >> 6;         // wave 0..3 -> n-slice [32*wv, 32*wv+32)
  const int l31 = lane & 31;
  const int l5 = lane >> 5;        // 0/1
  const int nb = wv * 32 + l31;    // this lane's n column (GEMM1) / n2 row-slice base

  // ---- persistent weight fragments (per-wave n-slice; live in AGPRs) ----
  v8bf B1[16], B2[8];
#pragma unroll
  for (int kt = 0; kt < 16; ++kt)
    B1[kt] = *reinterpret_cast<const v8bf*>(W1t + nb * 256 + kt * 16 + l5 * 8);
#pragma unroll
  for (int kt = 0; kt < 8; ++kt)
    B2[kt] = *reinterpret_cast<const v8bf*>(W2t + nb * 128 + kt * 16 + l5 * 8);
  const float b1v = b1[nb];
  const float bias3 = b3[0];

  // ---- per-lane GEMM3 constants: n2(r) = 32*wv + (r&3) + 8*(r>>2) + 4*l5 ----
  float w3r[16], b2r[16];
#pragma unroll
  for (int r = 0; r < 16; ++r) {
    int n2 = wv * 32 + (r & 3) + 8 * (r >> 2) + 4 * l5;
    w3r[r] = W3[n2];
    b2r[r] = b2[n2];
  }

  const int rslot = tid >> 4;      // 0..15: row slot within a gather pass
  const int lane16 = tid & 15;     // 16 lanes x 8 bf16 cover one 128-wide row

  // ---- preamble: xv = rows(t0), idxr = idx(t1) ----
  int idxr[8];
  uint4 xv[8];
  {
    const int t0 = min((int)blockIdx.x, ntiles - 1);
    const size_t e0 = (size_t)t0 * MTILE;
#pragma unroll
    for (int p = 0; p < 8; ++p) {
      int el = (p & 3) * 16 + rslot;
      idxr[p] = eidx[e0 + el + ((p >= 4) ? (size_t)E : 0)];
    }
#pragma unroll
    for (int p = 0; p < 8; ++p) {
      const unsigned short* xb = (p >= 4) ? xc2 : xc1;
      xv[p] = *reinterpret_cast<const uint4*>(xb + (size_t)idxr[p] * DIM + lane16 * 8);
    }
    const int t1 = min(t0 + (int)gridDim.x, ntiles - 1);
    const size_t e1 = (size_t)t1 * MTILE;
#pragma unroll
    for (int p = 0; p < 8; ++p) {
      int el = (p & 3) * 16 + rslot;
      idxr[p] = eidx[e1 + el + ((p >= 4) ? (size_t)E : 0)];
    }
  }

  int eprev = -1;  // edge base of the tile whose partials await final reduce

  for (int tile = blockIdx.x; tile < ntiles; tile += gridDim.x) {
    __syncthreads();  // syncA: pair free (GEMM1 readers done), partials ready

    // ---- store prefetched rows for THIS tile ----
#pragma unroll
    for (int p = 0; p < 8; ++p) {
      int el = (p & 3) * 16 + rslot;
      *reinterpret_cast<uint4*>(&sm_pair[el * PAIR_LD + ((p >= 4) ? 128 : 0) + lane16 * 8]) = xv[p];
    }

    // ---- deferred final reduce of PREVIOUS tile (wave 0 only) ----
    if (eprev >= 0 && tid < MTILE) {
      float s = sm_part[tid] + sm_part[64 + tid] + sm_part[128 + tid] + sm_part[192 + tid];
      out[eprev + tid] = s + bias3;
    }
    __syncthreads();  // syncB: pair ready

    // ---- GEMM1: h1 = relu(pair @ W1t^T), m-halves sequenced (16 live accs) ----
#pragma unroll
    for (int h = 0; h < 2; ++h) {
      v16f acc;
#pragma unroll
      for (int r = 0; r < 16; ++r) acc[r] = 0.f;
#pragma unroll
      for (int kt = 0; kt < 16; ++kt) {
        v8bf a = *reinterpret_cast<const v8bf*>(&sm_pair[(32 * h + l31) * PAIR_LD + kt * 16 + l5 * 8]);
        acc = __builtin_amdgcn_mfma_f32_32x32x16_bf16(a, B1[kt], acc, 0, 0, 0);
      }
#pragma unroll
      for (int r = 0; r < 16; ++r) {
        int m = 32 * h + (r & 3) + 8 * (r >> 2) + 4 * l5;  // C/D row map (m74/m101)
        sm_h1[m * H_LD + nb] = f2bf(fmaxf(acc[r] + b1v, 0.f));
      }
    }
    __syncthreads();  // syncC: h1 ready

    // ---- GEMM2 (transposed) + GEMM3 (in-register), per m-half ----
#pragma unroll
    for (int h = 0; h < 2; ++h) {
      v16f acc;
#pragma unroll
      for (int r = 0; r < 16; ++r) acc[r] = b2r[r];  // bias-init
#pragma unroll
      for (int kt = 0; kt < 8; ++kt) {
        // B-fragment = h1^T[k][m=32h+l31] == contiguous read of h1[32h+l31][k..]
        v8bf bf = *reinterpret_cast<const v8bf*>(&sm_h1[(32 * h + l31) * H_LD + kt * 16 + l5 * 8]);
        // A = W2t slice (persistent regs; A/B fragment layouts are symmetric)
        acc = __builtin_amdgcn_mfma_f32_32x32x16_bf16(B2[kt], bf, acc, 0, 0, 0);
      }
      // GEMM3: p = sum_r relu(h2^T[n2(r)][m]) * W3[n2(r)]
      float p = 0.f;
#pragma unroll
      for (int r = 0; r < 16; ++r) p += fmaxf(acc[r], 0.f) * w3r[r];
      p += __shfl_xor(p, 32);          // combine l5 halves (other 16 n2 rows)
      if (l5 == 0) sm_part[wv * 64 + 32 * h + l31] = p;
    }

    // ---- issue NEXT tile's gather loads (live only across store+barrier) ----
    {
      const int tn = min(tile + (int)gridDim.x, ntiles - 1);
      (void)tn;
#pragma unroll
      for (int p = 0; p < 8; ++p) {
        const unsigned short* xb = (p >= 4) ? xc2 : xc1;
        xv[p] = *reinterpret_cast<const uint4*>(xb + (size_t)idxr[p] * DIM + lane16 * 8);
      }
      const int t2 = min(tile + 2 * (int)gridDim.x, ntiles - 1);
      const size_t e2 = (size_t)t2 * MTILE;
#pragma unroll
      for (int p = 0; p < 8; ++p) {
        int el = (p & 3) * 16 + rslot;
        idxr[p] = eidx[e2 + el + ((p >= 4) ? (size_t)E : 0)];
      }
    }

    eprev = tile * MTILE;
  }

  // ---- epilogue: reduce the last tile's partials ----
  __syncthreads();
  if (eprev >= 0 && tid < MTILE) {
    float s = sm_part[tid] + sm_part[64 + tid] + sm_part[128 + tid] + sm_part[192 + tid];
    out[eprev + tid] = s + bias3;
  }
}

// Fallback (ws too small for node cache): r4 structure, fp32 gather+pack.
__global__ __launch_bounds__(256, 2) void mlp_edge_direct(
    const float* __restrict__ x1, const float* __restrict__ x2,
    const int* __restrict__ eidx,
    const unsigned short* __restrict__ W1t, const unsigned short* __restrict__ W2t,
    const float* __restrict__ b1, const float* __restrict__ b2,
    const float* __restrict__ W3, const float* __restrict__ b3,
    float* __restrict__ out, int E, int ntiles)
{
  __shared__ unsigned short sm_pair[MTILE * PAIR_LD];
  __shared__ unsigned short sm_h1[MTILE * H_LD];
  __shared__ float sm_w3[4 * 36];
  unsigned short* sm_h2 = sm_pair;

  const int tid = threadIdx.x;
  const int lane = tid & 63;
  const int wv = tid >> 6;
  const int l31 = lane & 31;
  const int l5 = lane >> 5;
  const int nb = wv * 32 + l31;

  v8bf B1[16], B2[8];
#pragma unroll
  for (int kt = 0; kt < 16; ++kt)
    B1[kt] = *reinterpret_cast<const v8bf*>(W1t + nb * 256 + kt * 16 + l5 * 8);
#pragma unroll
  for (int kt = 0; kt < 8; ++kt)
    B2[kt] = *reinterpret_cast<const v8bf*>(W2t + nb * 128 + kt * 16 + l5 * 8);
  const float b1v = b1[nb];
  const float b2v = b2[nb];
  const float bias3 = b3[0];
  if (tid < 128) sm_w3[(tid >> 5) * 36 + (tid & 31)] = W3[tid];

  const int rslot = tid >> 4;
  const int lane16 = tid & 15;
  const int part = tid & 3;

  for (int tile = blockIdx.x; tile < ntiles; tile += gridDim.x) {
    __syncthreads();
    const int e0 = tile * MTILE;
#pragma unroll
    for (int p = 0; p < 8; ++p) {
      int rowid = p * 16 + rslot;
      int half = rowid >> 6;
      int el = rowid & 63;
      int node = eidx[e0 + el + (half ? E : 0)];
      const float* src = (half ? x2 : x1) + (size_t)node * DIM + lane16 * 8;
      float4 f0 = *reinterpret_cast<const float4*>(src);
      float4 f1 = *reinterpret_cast<const float4*>(src + 4);
      uint4 pk;
      pk.x = f2bf_pack(f0.x, f0.y);
      pk.y = f2bf_pack(f0.z, f0.w);
      pk.z = f2bf_pack(f1.x, f1.y);
      pk.w = f2bf_pack(f1.z, f1.w);
      *reinterpret_cast<uint4*>(&sm_pair[el * PAIR_LD + half * 128 + lane16 * 8]) = pk;
    }
    __syncthreads();

    v16f acc0, acc1;
#pragma unroll
    for (int r = 0; r < 16; ++r) { acc0[r] = 0.f; acc1[r] = 0.f; }
#pragma unroll
    for (int kt = 0; kt < 16; ++kt) {
      v8bf a0 = *reinterpret_cast<const v8bf*>(&sm_pair[l31 * PAIR_LD + kt * 16 + l5 * 8]);
      v8bf a1 = *reinterpret_cast<const v8bf*>(&sm_pair[(32 + l31) * PAIR_LD + kt * 16 + l5 * 8]);
      acc0 = __builtin_amdgcn_mfma_f32_32x32x16_bf16(a0, B1[kt], acc0, 0, 0, 0);
      acc1 = __builtin_amdgcn_mfma_f32_32x32x16_bf16(a1, B1[kt], acc1, 0, 0, 0);
    }
#pragma unroll
    for (int r = 0; r < 16; ++r) {
      int m = (r & 3) + 8 * (r >> 2) + 4 * l5;
      sm_h1[m * H_LD + nb] = f2bf(fmaxf(acc0[r] + b1v, 0.f));
      sm_h1[(32 + m) * H_LD + nb] = f2bf(fmaxf(acc1[r] + b1v, 0.f));
    }
    __syncthreads();

    v16f c0, c1;
#pragma unroll
    for (int r = 0; r < 16; ++r) { c0[r] = 0.f; c1[r] = 0.f; }
#pragma unroll
    for (int kt = 0; kt < 8; ++kt) {
      v8bf a0 = *reinterpret_cast<const v8bf*>(&sm_h1[l31 * H_LD + kt * 16 + l5 * 8]);
      v8bf a1 = *reinterpret_cast<const v8bf*>(&sm_h1[(32 + l31) * H_LD + kt * 16 + l5 * 8]);
      c0 = __builtin_amdgcn_mfma_f32_32x32x16_bf16(a0, B2[kt], c0, 0, 0, 0);
      c1 = __builtin_amdgcn_mfma_f32_32x32x16_bf16(a1, B2[kt], c1, 0, 0, 0);
    }
#pragma unroll
    for (int r = 0; r < 16; ++r) {
      int m = (r & 3) + 8 * (r >> 2) + 4 * l5;
      sm_h2[m * H_LD + nb] = f2bf(fmaxf(c0[r] + b2v, 0.f));
      sm_h2[(32 + m) * H_LD + nb] = f2bf(fmaxf(c1[r] + b2v, 0.f));
    }
    __syncthreads();

    {
      int el = tid >> 2;
      const unsigned short* hrow = &sm_h2[el * H_LD + part * 32];
      const float* wrow = &sm_w3[part * 36];
      float sum = 0.f;
#pragma unroll
      for (int j = 0; j < 4; ++j) {
        uint4 u = *reinterpret_cast<const uint4*>(hrow + j * 8);
        float4 wa = *reinterpret_cast<const float4*>(wrow + j * 8);
        float4 wb = *reinterpret_cast<const float4*>(wrow + j * 8 + 4);
        sum += bfhi2f(u.x << 16) * wa.x + bfhi2f(u.x & 0xFFFF0000u) * wa.y;
        sum += bfhi2f(u.y << 16) * wa.z + bfhi2f(u.y & 0xFFFF0000u) * wa.w;
        sum += bfhi2f(u.z << 16) * wb.x + bfhi2f(u.z & 0xFFFF0000u) * wb.y;
        sum += bfhi2f(u.w << 16) * wb.z + bfhi2f(u.w & 0xFFFF0000u) * wb.w;
      }
      sum += __shfl_xor(sum, 1, 64);
      sum += __shfl_xor(sum, 2, 64);
      if (part == 0) out[e0 + el] = sum + bias3;
    }
  }
}

extern "C" void kernel_launch(void* const* d_in, const int* in_sizes, int n_in,
                              void* d_out, int out_size, void* d_ws, size_t ws_size,
                              hipStream_t stream) {
  const float* x1 = (const float*)d_in[0];
  const float* x2 = (const float*)d_in[1];
  const int* eidx = (const int*)d_in[2];
  const float* W1 = (const float*)d_in[3];
  const float* b1 = (const float*)d_in[4];
  const float* W2 = (const float*)d_in[5];
  const float* b2 = (const float*)d_in[6];
  const float* W3 = (const float*)d_in[7];
  const float* b3 = (const float*)d_in[8];
  float* out = (float*)d_out;

  int E = in_sizes[2] / 2;
  if (E <= 0) return;
  int ntiles = E / MTILE;           // E = 1,600,000 divisible by 64
  int nelem = in_sizes[0];          // nodes * DIM
  int n8 = nelem / 8;

  unsigned short* W1t = (unsigned short*)d_ws;         // 32768 bf16
  unsigned short* W2t = W1t + 32768;                   // 16384 bf16
  size_t woff = 98304;                                 // bytes used by weights
  size_t need = woff + 2 * (size_t)nelem * 2;
  int use_cache = (ws_size >= need) ? 1 : 0;
  unsigned short* xc1 = (unsigned short*)((char*)d_ws + woff);
  unsigned short* xc2 = xc1 + nelem;

  int prep_items = 49152 + (use_cache ? 2 * n8 : 0);
  prep_all<<<(prep_items + 255) / 256, 256, 0, stream>>>(
      W1, W2, x1, x2, W1t, W2t, xc1, xc2, n8, use_cache);

  if (use_cache) {
    mlp_edge_cached<<<768, 256, 0, stream>>>(eidx, W1t, W2t, b1, b2, W3, b3,
                                             out, E, ntiles, xc1, xc2);
  } else {
    mlp_edge_direct<<<768, 256, 0, stream>>>(x1, x2, eidx, W1t, W2t,
                                             b1, b2, W3, b3, out, E, ntiles);
  }
}

// Round 6
// 318.547 us; speedup vs baseline: 1.8284x; 1.8284x over previous
//
#include <hip/hip_runtime.h>
#include <cstdint>

#define DIM 128
#define MTILE 64        // edges per block-tile
#define PAIR_LD 264     // ushorts per pair row (256 + 8 pad, keeps 16B align)
#define H_LD 136        // ushorts per h row  (128 + 8 pad)

typedef __bf16 v8bf __attribute__((ext_vector_type(8)));
typedef float v16f __attribute__((ext_vector_type(16)));

static __device__ __forceinline__ unsigned int f2bf_pack(float a, float b) {
  union { float f; unsigned u; } x, y; x.f = a; y.f = b;
  unsigned lo = (x.u + 0x7FFFu + ((x.u >> 16) & 1u)) >> 16;
  unsigned hi = (y.u + 0x7FFFu + ((y.u >> 16) & 1u)) >> 16;
  return lo | (hi << 16);
}
static __device__ __forceinline__ unsigned short f2bf(float a) {
  union { float f; unsigned u; } x; x.f = a;
  return (unsigned short)((x.u + 0x7FFFu + ((x.u >> 16) & 1u)) >> 16);
}
static __device__ __forceinline__ float bfhi2f(unsigned int hi16) {
  union { unsigned u; float f; } c; c.u = hi16; return c.f;
}

// One fused prep launch:
//  [0, 32768)          : W1 [256][128] -> W1t bf16 [128][256] (transpose+convert)
//  [32768, 49152)      : W2 [128][128] -> W2t bf16 [128][128]
//  [49152, 49152+n8)   : x1 fp32 -> xc1 bf16, 8 elems/thread
//  [.., 49152+2*n8)    : x2 fp32 -> xc2 bf16
__global__ __launch_bounds__(256) void prep_all(
    const float* __restrict__ W1, const float* __restrict__ W2,
    const float* __restrict__ x1, const float* __restrict__ x2,
    unsigned short* __restrict__ W1t, unsigned short* __restrict__ W2t,
    unsigned short* __restrict__ xc1, unsigned short* __restrict__ xc2,
    int n8, int use_cache) {
  int i = blockIdx.x * 256 + threadIdx.x;
  if (i < 32768) {
    int n = i >> 8, k = i & 255;
    W1t[i] = f2bf(W1[k * 128 + n]);
  } else if (i < 49152) {
    int j = i - 32768;
    int n = j >> 7, k = j & 127;
    W2t[j] = f2bf(W2[k * 128 + n]);
  } else if (use_cache) {
    int j = i - 49152;
    const float* xs;
    unsigned short* xd;
    if (j < n8) { xs = x1; xd = xc1; }
    else if (j < 2 * n8) { xs = x2; xd = xc2; j -= n8; }
    else return;
    const float4* s = reinterpret_cast<const float4*>(xs) + (size_t)j * 2;
    float4 f0 = s[0];
    float4 f1 = s[1];
    uint4 pk;
    pk.x = f2bf_pack(f0.x, f0.y);
    pk.y = f2bf_pack(f0.z, f0.w);
    pk.z = f2bf_pack(f1.x, f1.y);
    pk.w = f2bf_pack(f1.z, f1.w);
    reinterpret_cast<uint4*>(xd)[j] = pk;
  }
}

// Round-6: r5's transposed-GEMM2 structure (validated correct) with r4's
// proven-clean register discipline:
//   ALLOCATOR RULE (r2-r5 evidence): ~128 persistent weight regs are fine;
//   any extra >=32-reg payload held across a barrier/MFMA region -> scratch
//   spill (r2:839MB, r3:805MB, r5:625MB of WRITE). So gather x-rows are
//   loaded AND stored to LDS within ~10 instrs (r4 style); only the 8 node
//   indices (scalar ints) are prefetched across the tile.
__global__ __launch_bounds__(256, 2) void mlp_edge_cached(
    const int* __restrict__ eidx,
    const unsigned short* __restrict__ W1t, const unsigned short* __restrict__ W2t,
    const float* __restrict__ b1, const float* __restrict__ b2,
    const float* __restrict__ W3, const float* __restrict__ b3,
    float* __restrict__ out, int E, int ntiles,
    const unsigned short* __restrict__ xc1, const unsigned short* __restrict__ xc2)
{
  __shared__ unsigned short sm_pair[MTILE * PAIR_LD];  // 33792 B
  __shared__ unsigned short sm_h1[MTILE * H_LD];       // 17408 B
  __shared__ float sm_part[4 * MTILE];                 // 1024 B: [wave][edge]

  const int tid = threadIdx.x;
  const int lane = tid & 63;
  const int wv = tid >> 6;         // wave 0..3 -> n-slice [32*wv, 32*wv+32)
  const int l31 = lane & 31;
  const int l5 = lane >> 5;        // 0/1
  const int nb = wv * 32 + l31;    // this lane's n column slice base

  // ---- persistent weight fragments (per-wave n-slice) ----
  v8bf B1[16], B2[8];
#pragma unroll
  for (int kt = 0; kt < 16; ++kt)
    B1[kt] = *reinterpret_cast<const v8bf*>(W1t + nb * 256 + kt * 16 + l5 * 8);
#pragma unroll
  for (int kt = 0; kt < 8; ++kt)
    B2[kt] = *reinterpret_cast<const v8bf*>(W2t + nb * 128 + kt * 16 + l5 * 8);
  const float b1v = b1[nb];
  const float bias3 = b3[0];

  // ---- per-lane GEMM3 constants: n2(r) = 32*wv + (r&3) + 8*(r>>2) + 4*l5 ----
  float w3r[16], b2r[16];
#pragma unroll
  for (int r = 0; r < 16; ++r) {
    int n2 = wv * 32 + (r & 3) + 8 * (r >> 2) + 4 * l5;
    w3r[r] = W3[n2];
    b2r[r] = b2[n2];
  }

  const int rslot = tid >> 4;      // 0..15: row slot within a gather pass
  const int lane16 = tid & 15;     // 16 lanes x 8 bf16 cover one 128-wide row

  // ---- preamble: idxr = indices for the FIRST tile ----
  int idxr[8];
  {
    const int t0 = min((int)blockIdx.x, ntiles - 1);
    const size_t e0 = (size_t)t0 * MTILE;
#pragma unroll
    for (int p = 0; p < 8; ++p) {
      int el = (p & 3) * 16 + rslot;
      idxr[p] = eidx[e0 + el + ((p >= 4) ? (size_t)E : 0)];
    }
  }

  int eprev = -1;  // edge base of the tile whose partials await final reduce

  for (int tile = blockIdx.x; tile < ntiles; tile += gridDim.x) {
    __syncthreads();  // syncA: pair free (GEMM1 readers done), partials ready

    // ---- gather: issue loads (idx already in regs), overlap with reduce ----
    uint4 xv[8];
#pragma unroll
    for (int p = 0; p < 8; ++p) {
      const unsigned short* xb = (p >= 4) ? xc2 : xc1;
      xv[p] = *reinterpret_cast<const uint4*>(xb + (size_t)idxr[p] * DIM + lane16 * 8);
    }

    // ---- deferred final reduce of PREVIOUS tile (one thread per edge) ----
    if (eprev >= 0 && tid < MTILE) {
      float s = sm_part[tid] + sm_part[64 + tid] + sm_part[128 + tid] + sm_part[192 + tid];
      out[eprev + tid] = s + bias3;
    }

    // ---- store gathered rows (short live range -- no spill) ----
#pragma unroll
    for (int p = 0; p < 8; ++p) {
      int el = (p & 3) * 16 + rslot;
      *reinterpret_cast<uint4*>(&sm_pair[el * PAIR_LD + ((p >= 4) ? 128 : 0) + lane16 * 8]) = xv[p];
    }

    // ---- prefetch next tile's indices (8 scalar ints, land during GEMMs) ----
    {
      const int tn = min(tile + (int)gridDim.x, ntiles - 1);
      const size_t en = (size_t)tn * MTILE;
#pragma unroll
      for (int p = 0; p < 8; ++p) {
        int el = (p & 3) * 16 + rslot;
        idxr[p] = eidx[en + el + ((p >= 4) ? (size_t)E : 0)];
      }
    }
    __syncthreads();  // syncB: pair ready

    // ---- GEMM1: h1 = relu(pair @ W1), m-halves sequenced (16 live accs) ----
#pragma unroll
    for (int h = 0; h < 2; ++h) {
      v16f acc;
#pragma unroll
      for (int r = 0; r < 16; ++r) acc[r] = 0.f;
#pragma unroll
      for (int kt = 0; kt < 16; ++kt) {
        v8bf a = *reinterpret_cast<const v8bf*>(&sm_pair[(32 * h + l31) * PAIR_LD + kt * 16 + l5 * 8]);
        acc = __builtin_amdgcn_mfma_f32_32x32x16_bf16(a, B1[kt], acc, 0, 0, 0);
      }
#pragma unroll
      for (int r = 0; r < 16; ++r) {
        int m = 32 * h + (r & 3) + 8 * (r >> 2) + 4 * l5;  // C/D row map (m74/m101)
        sm_h1[m * H_LD + nb] = f2bf(fmaxf(acc[r] + b1v, 0.f));
      }
    }
    __syncthreads();  // syncC: h1 ready

    // ---- GEMM2 (transposed: h2^T = W2t @ h1^T) + GEMM3 in-register ----
#pragma unroll
    for (int h = 0; h < 2; ++h) {
      v16f acc;
#pragma unroll
      for (int r = 0; r < 16; ++r) acc[r] = b2r[r];  // bias-init
#pragma unroll
      for (int kt = 0; kt < 8; ++kt) {
        // B-fragment = h1^T[k][m=32h+l31] == contiguous read of h1[32h+l31][k..]
        v8bf bf = *reinterpret_cast<const v8bf*>(&sm_h1[(32 * h + l31) * H_LD + kt * 16 + l5 * 8]);
        acc = __builtin_amdgcn_mfma_f32_32x32x16_bf16(B2[kt], bf, acc, 0, 0, 0);
      }
      // GEMM3: p = sum_r relu(h2^T[n2(r)][m]) * W3[n2(r)]
      float p = 0.f;
#pragma unroll
      for (int r = 0; r < 16; ++r) p += fmaxf(acc[r], 0.f) * w3r[r];
      p += __shfl_xor(p, 32);          // combine l5 halves (other 16 n2 rows)
      if (l5 == 0) sm_part[wv * 64 + 32 * h + l31] = p;
    }

    eprev = tile * MTILE;
  }

  // ---- epilogue: reduce the last tile's partials ----
  __syncthreads();
  if (eprev >= 0 && tid < MTILE) {
    float s = sm_part[tid] + sm_part[64 + tid] + sm_part[128 + tid] + sm_part[192 + tid];
    out[eprev + tid] = s + bias3;
  }
}

// Fallback (ws too small for node cache): r4 structure, fp32 gather+pack.
__global__ __launch_bounds__(256, 2) void mlp_edge_direct(
    const float* __restrict__ x1, const float* __restrict__ x2,
    const int* __restrict__ eidx,
    const unsigned short* __restrict__ W1t, const unsigned short* __restrict__ W2t,
    const float* __restrict__ b1, const float* __restrict__ b2,
    const float* __restrict__ W3, const float* __restrict__ b3,
    float* __restrict__ out, int E, int ntiles)
{
  __shared__ unsigned short sm_pair[MTILE * PAIR_LD];
  __shared__ unsigned short sm_h1[MTILE * H_LD];
  __shared__ float sm_w3[4 * 36];
  unsigned short* sm_h2 = sm_pair;

  const int tid = threadIdx.x;
  const int lane = tid & 63;
  const int wv = tid >> 6;
  const int l31 = lane & 31;
  const int l5 = lane >> 5;
  const int nb = wv * 32 + l31;

  v8bf B1[16], B2[8];
#pragma unroll
  for (int kt = 0; kt < 16; ++kt)
    B1[kt] = *reinterpret_cast<const v8bf*>(W1t + nb * 256 + kt * 16 + l5 * 8);
#pragma unroll
  for (int kt = 0; kt < 8; ++kt)
    B2[kt] = *reinterpret_cast<const v8bf*>(W2t + nb * 128 + kt * 16 + l5 * 8);
  const float b1v = b1[nb];
  const float b2v = b2[nb];
  const float bias3 = b3[0];
  if (tid < 128) sm_w3[(tid >> 5) * 36 + (tid & 31)] = W3[tid];

  const int rslot = tid >> 4;
  const int lane16 = tid & 15;
  const int part = tid & 3;

  for (int tile = blockIdx.x; tile < ntiles; tile += gridDim.x) {
    __syncthreads();
    const int e0 = tile * MTILE;
#pragma unroll
    for (int p = 0; p < 8; ++p) {
      int rowid = p * 16 + rslot;
      int half = rowid >> 6;
      int el = rowid & 63;
      int node = eidx[e0 + el + (half ? E : 0)];
      const float* src = (half ? x2 : x1) + (size_t)node * DIM + lane16 * 8;
      float4 f0 = *reinterpret_cast<const float4*>(src);
      float4 f1 = *reinterpret_cast<const float4*>(src + 4);
      uint4 pk;
      pk.x = f2bf_pack(f0.x, f0.y);
      pk.y = f2bf_pack(f0.z, f0.w);
      pk.z = f2bf_pack(f1.x, f1.y);
      pk.w = f2bf_pack(f1.z, f1.w);
      *reinterpret_cast<uint4*>(&sm_pair[el * PAIR_LD + half * 128 + lane16 * 8]) = pk;
    }
    __syncthreads();

    v16f acc0, acc1;
#pragma unroll
    for (int r = 0; r < 16; ++r) { acc0[r] = 0.f; acc1[r] = 0.f; }
#pragma unroll
    for (int kt = 0; kt < 16; ++kt) {
      v8bf a0 = *reinterpret_cast<const v8bf*>(&sm_pair[l31 * PAIR_LD + kt * 16 + l5 * 8]);
      v8bf a1 = *reinterpret_cast<const v8bf*>(&sm_pair[(32 + l31) * PAIR_LD + kt * 16 + l5 * 8]);
      acc0 = __builtin_amdgcn_mfma_f32_32x32x16_bf16(a0, B1[kt], acc0, 0, 0, 0);
      acc1 = __builtin_amdgcn_mfma_f32_32x32x16_bf16(a1, B1[kt], acc1, 0, 0, 0);
    }
#pragma unroll
    for (int r = 0; r < 16; ++r) {
      int m = (r & 3) + 8 * (r >> 2) + 4 * l5;
      sm_h1[m * H_LD + nb] = f2bf(fmaxf(acc0[r] + b1v, 0.f));
      sm_h1[(32 + m) * H_LD + nb] = f2bf(fmaxf(acc1[r] + b1v, 0.f));
    }
    __syncthreads();

    v16f c0, c1;
#pragma unroll
    for (int r = 0; r < 16; ++r) { c0[r] = 0.f; c1[r] = 0.f; }
#pragma unroll
    for (int kt = 0; kt < 8; ++kt) {
      v8bf a0 = *reinterpret_cast<const v8bf*>(&sm_h1[l31 * H_LD + kt * 16 + l5 * 8]);
      v8bf a1 = *reinterpret_cast<const v8bf*>(&sm_h1[(32 + l31) * H_LD + kt * 16 + l5 * 8]);
      c0 = __builtin_amdgcn_mfma_f32_32x32x16_bf16(a0, B2[kt], c0, 0, 0, 0);
      c1 = __builtin_amdgcn_mfma_f32_32x32x16_bf16(a1, B2[kt], c1, 0, 0, 0);
    }
#pragma unroll
    for (int r = 0; r < 16; ++r) {
      int m = (r & 3) + 8 * (r >> 2) + 4 * l5;
      sm_h2[m * H_LD + nb] = f2bf(fmaxf(c0[r] + b2v, 0.f));
      sm_h2[(32 + m) * H_LD + nb] = f2bf(fmaxf(c1[r] + b2v, 0.f));
    }
    __syncthreads();

    {
      int el = tid >> 2;
      const unsigned short* hrow = &sm_h2[el * H_LD + part * 32];
      const float* wrow = &sm_w3[part * 36];
      float sum = 0.f;
#pragma unroll
      for (int j = 0; j < 4; ++j) {
        uint4 u = *reinterpret_cast<const uint4*>(hrow + j * 8);
        float4 wa = *reinterpret_cast<const float4*>(wrow + j * 8);
        float4 wb = *reinterpret_cast<const float4*>(wrow + j * 8 + 4);
        sum += bfhi2f(u.x << 16) * wa.x + bfhi2f(u.x & 0xFFFF0000u) * wa.y;
        sum += bfhi2f(u.y << 16) * wa.z + bfhi2f(u.y & 0xFFFF0000u) * wa.w;
        sum += bfhi2f(u.z << 16) * wb.x + bfhi2f(u.z & 0xFFFF0000u) * wb.y;
        sum += bfhi2f(u.w << 16) * wb.z + bfhi2f(u.w & 0xFFFF0000u) * wb.w;
      }
      sum += __shfl_xor(sum, 1, 64);
      sum += __shfl_xor(sum, 2, 64);
      if (part == 0) out[e0 + el] = sum + bias3;
    }
  }
}

extern "C" void kernel_launch(void* const* d_in, const int* in_sizes, int n_in,
                              void* d_out, int out_size, void* d_ws, size_t ws_size,
                              hipStream_t stream) {
  const float* x1 = (const float*)d_in[0];
  const float* x2 = (const float*)d_in[1];
  const int* eidx = (const int*)d_in[2];
  const float* W1 = (const float*)d_in[3];
  const float* b1 = (const float*)d_in[4];
  const float* W2 = (const float*)d_in[5];
  const float* b2 = (const float*)d_in[6];
  const float* W3 = (const float*)d_in[7];
  const float* b3 = (const float*)d_in[8];
  float* out = (float*)d_out;

  int E = in_sizes[2] / 2;
  if (E <= 0) return;
  int ntiles = E / MTILE;           // E = 1,600,000 divisible by 64
  int nelem = in_sizes[0];          // nodes * DIM
  int n8 = nelem / 8;

  unsigned short* W1t = (unsigned short*)d_ws;         // 32768 bf16
  unsigned short* W2t = W1t + 32768;                   // 16384 bf16
  size_t woff = 98304;                                 // bytes used by weights
  size_t need = woff + 2 * (size_t)nelem * 2;
  int use_cache = (ws_size >= need) ? 1 : 0;
  unsigned short* xc1 = (unsigned short*)((char*)d_ws + woff);
  unsigned short* xc2 = xc1 + nelem;

  int prep_items = 49152 + (use_cache ? 2 * n8 : 0);
  prep_all<<<(prep_items + 255) / 256, 256, 0, stream>>>(
      W1, W2, x1, x2, W1t, W2t, xc1, xc2, n8, use_cache);

  if (use_cache) {
    mlp_edge_cached<<<512, 256, 0, stream>>>(eidx, W1t, W2t, b1, b2, W3, b3,
                                             out, E, ntiles, xc1, xc2);
  } else {
    mlp_edge_direct<<<512, 256, 0, stream>>>(x1, x2, eidx, W1t, W2t,
                                             b1, b2, W3, b3, out, E, ntiles);
  }
}